// Round 1
// baseline (206.873 us; speedup 1.0000x reference)
//
#include <hip/hip_runtime.h>

typedef __bf16 bf16;
typedef __bf16 bf16x4 __attribute__((ext_vector_type(4)));
typedef __bf16 bf16x8 __attribute__((ext_vector_type(8)));
typedef float f32x4 __attribute__((ext_vector_type(4)));

static constexpr int Bn = 2, Sn = 2048, Dn = 1024, Hn = 16, HDn = 64;

__device__ __forceinline__ void gload_lds16(const void* g, void* l) {
  __builtin_amdgcn_global_load_lds((__attribute__((address_space(1))) void*)g,
                                   (__attribute__((address_space(3))) void*)l, 16, 0, 0);
}

__device__ __forceinline__ f32x4 mfma_bf16_16x16x32(bf16x8 a, bf16x8 b, f32x4 c) {
  return __builtin_amdgcn_mfma_f32_16x16x32_bf16(a, b, c, 0, 0, 0);
}

// ---------------- fp32 -> bf16 convert (with optional scale) ----------------
__global__ __launch_bounds__(256) void cvt_f32_to_bf16(const float* __restrict__ in,
                                                       bf16* __restrict__ out,
                                                       int n4, float scale) {
  int i = blockIdx.x * 256 + threadIdx.x;
  const int stride = gridDim.x * 256;
  for (; i < n4; i += stride) {
    float4 v = reinterpret_cast<const float4*>(in)[i];
    bf16x4 o;
    o[0] = (bf16)(v.x * scale);
    o[1] = (bf16)(v.y * scale);
    o[2] = (bf16)(v.z * scale);
    o[3] = (bf16)(v.w * scale);
    reinterpret_cast<bf16x4*>(out)[i] = o;
  }
}

// ---------------- GEMM: C[M,N] = A[M,K] * B[N,K]^T  (m97 structure) ----------------
__device__ __forceinline__ void store_out(float* C, size_t i, float v) { C[i] = v; }
__device__ __forceinline__ void store_out(bf16* C, size_t i, float v) { C[i] = (bf16)v; }

template <typename OutT>
__device__ __forceinline__ void gemm_bt_dev(const bf16* __restrict__ A,
                                            const bf16* __restrict__ Bw,
                                            OutT* __restrict__ C,
                                            int K, int N) {
  const int t = threadIdx.x;
  const int l = t & 63, w = t >> 6;
  const int wr = w >> 1, wc = w & 1;
  const int lc = l & 15, lg = l >> 4;
  const int row0 = blockIdx.y * 128;
  const int col0 = blockIdx.x * 128;

  __shared__ bf16 As[128 * 32];
  __shared__ bf16 Bs[128 * 32];

  f32x4 acc[4][4] = {};

  for (int k0 = 0; k0 < K; k0 += 32) {
#pragma unroll
    for (int i = 0; i < 2; ++i) {
      const int c = i * 256 + t;          // 16B chunk id, 512 total
      const int r = c >> 2;               // tile row (4 chunks / 64B row)
      const int scc = (c & 3) ^ (r & 3);  // source chunk: XOR-swizzle
      gload_lds16(A + (size_t)(row0 + r) * K + k0 + scc * 8, As + c * 8);
      gload_lds16(Bw + (size_t)(col0 + r) * K + k0 + scc * 8, Bs + c * 8);
    }
    __syncthreads();  // drains vmcnt -> LDS visible

    bf16x8 af[4], bfr[4];
#pragma unroll
    for (int m = 0; m < 4; ++m) {
      const int r = wr * 64 + m * 16 + lc;
      af[m] = *reinterpret_cast<const bf16x8*>(As + r * 32 + ((lg ^ (r & 3)) * 8));
    }
#pragma unroll
    for (int n = 0; n < 4; ++n) {
      const int r = wc * 64 + n * 16 + lc;
      bfr[n] = *reinterpret_cast<const bf16x8*>(Bs + r * 32 + ((lg ^ (r & 3)) * 8));
    }
#pragma unroll
    for (int m = 0; m < 4; ++m)
#pragma unroll
      for (int n = 0; n < 4; ++n)
        acc[m][n] = mfma_bf16_16x16x32(af[m], bfr[n], acc[m][n]);
    __syncthreads();
  }

#pragma unroll
  for (int m = 0; m < 4; ++m) {
    const int rbase = row0 + wr * 64 + m * 16 + lg * 4;
#pragma unroll
    for (int n = 0; n < 4; ++n) {
      const int col = col0 + wc * 64 + n * 16 + lc;
#pragma unroll
      for (int j = 0; j < 4; ++j)
        store_out(C, (size_t)(rbase + j) * N + col, acc[m][n][j]);
    }
  }
}

__global__ __launch_bounds__(256) void gemm_qkv(
    const bf16* __restrict__ qa, const bf16* __restrict__ wq, bf16* __restrict__ qo,
    const bf16* __restrict__ ka, const bf16* __restrict__ wk, bf16* __restrict__ ko,
    const bf16* __restrict__ va, const bf16* __restrict__ wv, bf16* __restrict__ vo) {
  const bf16 *A, *Bw;
  bf16* C;
  if (blockIdx.z == 0)      { A = qa; Bw = wq; C = qo; }
  else if (blockIdx.z == 1) { A = ka; Bw = wk; C = ko; }
  else                      { A = va; Bw = wv; C = vo; }
  gemm_bt_dev<bf16>(A, Bw, C, Dn, Dn);
}

__global__ __launch_bounds__(256) void gemm_out_f32(const bf16* __restrict__ A,
                                                    const bf16* __restrict__ Bw,
                                                    float* __restrict__ C) {
  gemm_bt_dev<float>(A, Bw, C, Dn, Dn);
}

// ---------------- per-batch transpose (S x D) -> (D x S) for V ----------------
__global__ __launch_bounds__(256) void transpose_bsd(const bf16* __restrict__ in,
                                                     bf16* __restrict__ out) {
  __shared__ bf16 tile[64][66];  // 66: odd-ish stride -> spread banks on column reads
  const int s0 = blockIdx.x * 64, d0 = blockIdx.y * 64, b = blockIdx.z;
  const int t = threadIdx.x;
#pragma unroll
  for (int i = 0; i < 2; ++i) {
    const int c = i * 256 + t;
    const int r = c >> 3, cc = (c & 7) * 8;
    const bf16x8 v = *reinterpret_cast<const bf16x8*>(
        in + ((size_t)b * Sn + s0 + r) * Dn + d0 + cc);
#pragma unroll
    for (int j = 0; j < 8; ++j) tile[r][cc + j] = v[j];
  }
  __syncthreads();
#pragma unroll
  for (int i = 0; i < 2; ++i) {
    const int c = i * 256 + t;
    const int r = c >> 3, cc = (c & 7) * 8;  // r = d-local, cc.. = s-local
    bf16x8 v;
#pragma unroll
    for (int j = 0; j < 8; ++j) v[j] = tile[cc + j][r];
    *reinterpret_cast<bf16x8*>(out + ((size_t)b * Dn + d0 + r) * Sn + s0 + cc) = v;
  }
}

// ---------------- causal flash attention ----------------
// qp,kp: (B,S,D) bf16 (qp pre-scaled by 1/8 via Wq); vt: (B,D,S) bf16; ctx: (B,S,D) bf16
__global__ __launch_bounds__(256) void flash_attn(const bf16* __restrict__ qp,
                                                  const bf16* __restrict__ kp,
                                                  const bf16* __restrict__ vt,
                                                  bf16* __restrict__ ctx) {
  const int qt = blockIdx.x;   // S/128 = 16
  const int h  = blockIdx.y;   // 16
  const int b  = blockIdx.z;   // 2
  const int q0 = qt * 128;
  const int t = threadIdx.x, w = t >> 6, l = t & 63;
  const int lc = l & 15, lg = l >> 4;
  const int qbase = q0 + w * 32;  // each wave owns 32 Q rows

  __shared__ bf16 Klds[64 * 64];      // [kv][d], chunk-swizzled
  __shared__ bf16 Vlds[64 * 64];      // [d][kv], chunk-swizzled
  __shared__ bf16 Plds[4][32 * 72];   // per-wave P, stride 72 (144B, 16B-aligned)

  // Q fragments in registers (A-operand layout)
  bf16x8 qf[2][2];
#pragma unroll
  for (int m = 0; m < 2; ++m)
#pragma unroll
    for (int kk = 0; kk < 2; ++kk) {
      const int qrow = qbase + m * 16 + lc;
      qf[m][kk] = *reinterpret_cast<const bf16x8*>(
          qp + ((size_t)b * Sn + qrow) * Dn + h * HDn + kk * 32 + lg * 8);
    }

  float mrow[2][4], lrow[2][4];
  f32x4 oacc[2][4] = {};
#pragma unroll
  for (int m = 0; m < 2; ++m)
#pragma unroll
    for (int j = 0; j < 4; ++j) { mrow[m][j] = -1e30f; lrow[m][j] = 0.0f; }

  const int nkv = qt * 2 + 2;
  for (int kt = 0; kt < nkv; ++kt) {
    const int kv0 = kt * 64;
    // stage K and Vt tiles, source pre-swizzled (chunk ^= row&7) for conflict-free reads
#pragma unroll
    for (int i = 0; i < 2; ++i) {
      const int c = i * 256 + t;
      const int r = c >> 3;
      const int scc = (c & 7) ^ (r & 7);
      gload_lds16(kp + ((size_t)b * Sn + kv0 + r) * Dn + h * HDn + scc * 8, Klds + c * 8);
      gload_lds16(vt + ((size_t)b * Dn + h * HDn + r) * Sn + kv0 + scc * 8, Vlds + c * 8);
    }
    __syncthreads();

    if (kv0 <= qbase + 31) {  // wave-uniform causal skip
      // S = Q K^T (32 x 64)
      f32x4 sc[2][4] = {};
#pragma unroll
      for (int kk = 0; kk < 2; ++kk) {
#pragma unroll
        for (int n = 0; n < 4; ++n) {
          const int r = n * 16 + lc;
          const int off = (r << 7) + (((kk * 4 + lg) ^ (r & 7)) << 4);
          const bf16x8 kf = *reinterpret_cast<const bf16x8*>(
              reinterpret_cast<const char*>(Klds) + off);
          sc[0][n] = mfma_bf16_16x16x32(qf[0][kk], kf, sc[0][n]);
          sc[1][n] = mfma_bf16_16x16x32(qf[1][kk], kf, sc[1][n]);
        }
      }
      // causal mask (only for diagonal-crossing tiles)
      if (kv0 + 63 > qbase) {
#pragma unroll
        for (int m = 0; m < 2; ++m) {
          const int rg = qbase + m * 16 + lg * 4;
#pragma unroll
          for (int n = 0; n < 4; ++n) {
            const int cg = kv0 + n * 16 + lc;
#pragma unroll
            for (int j = 0; j < 4; ++j)
              if (cg > rg + j) sc[m][n][j] = -1e30f;
          }
        }
      }
      // online softmax, wave-parallel (16-lane shfl reduce)
#pragma unroll
      for (int m = 0; m < 2; ++m) {
        float tmax[4], rsum[4], alpha[4];
#pragma unroll
        for (int j = 0; j < 4; ++j)
          tmax[j] = fmaxf(fmaxf(sc[m][0][j], sc[m][1][j]),
                          fmaxf(sc[m][2][j], sc[m][3][j]));
#pragma unroll
        for (int dd = 1; dd < 16; dd <<= 1)
#pragma unroll
          for (int j = 0; j < 4; ++j)
            tmax[j] = fmaxf(tmax[j], __shfl_xor(tmax[j], dd, 64));
#pragma unroll
        for (int j = 0; j < 4; ++j) {
          const float mn = fmaxf(mrow[m][j], tmax[j]);
          alpha[j] = __expf(mrow[m][j] - mn);
          mrow[m][j] = mn;
          rsum[j] = 0.0f;
        }
#pragma unroll
        for (int n = 0; n < 4; ++n)
#pragma unroll
          for (int j = 0; j < 4; ++j) {
            const float pe = __expf(sc[m][n][j] - mrow[m][j]);
            sc[m][n][j] = pe;
            rsum[j] += pe;
          }
#pragma unroll
        for (int dd = 1; dd < 16; dd <<= 1)
#pragma unroll
          for (int j = 0; j < 4; ++j)
            rsum[j] += __shfl_xor(rsum[j], dd, 64);
#pragma unroll
        for (int j = 0; j < 4; ++j)
          lrow[m][j] = lrow[m][j] * alpha[j] + rsum[j];
#pragma unroll
        for (int n = 0; n < 4; ++n)
#pragma unroll
          for (int j = 0; j < 4; ++j)
            oacc[m][n][j] *= alpha[j];
        // P -> LDS (bf16), per-wave slab
#pragma unroll
        for (int n = 0; n < 4; ++n)
#pragma unroll
          for (int j = 0; j < 4; ++j)
            Plds[w][(m * 16 + lg * 4 + j) * 72 + n * 16 + lc] = (bf16)sc[m][n][j];
      }
      asm volatile("s_waitcnt lgkmcnt(0)" ::: "memory");  // cross-lane P visibility
      // O += P V
#pragma unroll
      for (int kk = 0; kk < 2; ++kk) {
        const bf16x8 pa0 = *reinterpret_cast<const bf16x8*>(
            &Plds[w][lc * 72 + kk * 32 + lg * 8]);
        const bf16x8 pa1 = *reinterpret_cast<const bf16x8*>(
            &Plds[w][(16 + lc) * 72 + kk * 32 + lg * 8]);
#pragma unroll
        for (int nd = 0; nd < 4; ++nd) {
          const int r = nd * 16 + lc;
          const int off = (r << 7) + (((kk * 4 + lg) ^ (r & 7)) << 4);
          const bf16x8 vb = *reinterpret_cast<const bf16x8*>(
              reinterpret_cast<const char*>(Vlds) + off);
          oacc[0][nd] = mfma_bf16_16x16x32(pa0, vb, oacc[0][nd]);
          oacc[1][nd] = mfma_bf16_16x16x32(pa1, vb, oacc[1][nd]);
        }
      }
    }
    __syncthreads();
  }

  // epilogue: O / l -> ctx (bf16)
#pragma unroll
  for (int m = 0; m < 2; ++m)
#pragma unroll
    for (int j = 0; j < 4; ++j) {
      const float inv = 1.0f / lrow[m][j];
      const int rg = qbase + m * 16 + lg * 4 + j;
#pragma unroll
      for (int nd = 0; nd < 4; ++nd)
        ctx[((size_t)b * Sn + rg) * Dn + h * HDn + nd * 16 + lc] =
            (bf16)(oacc[m][nd][j] * inv);
    }
}

// ---------------- launch ----------------
extern "C" void kernel_launch(void* const* d_in, const int* in_sizes, int n_in,
                              void* d_out, int out_size, void* d_ws, size_t ws_size,
                              hipStream_t stream) {
  const float* q  = (const float*)d_in[0];
  const float* k  = (const float*)d_in[1];
  const float* v  = (const float*)d_in[2];
  // d_in[3] = causal mask (structure known; unused)
  const float* Wq = (const float*)d_in[4];
  const float* Wk = (const float*)d_in[5];
  const float* Wv = (const float*)d_in[6];
  const float* Wo = (const float*)d_in[7];

  constexpr size_t BSD = (size_t)Bn * Sn * Dn;  // 4,194,304
  constexpr size_t DD  = (size_t)Dn * Dn;       // 1,048,576

  char* p = (char*)d_ws;
  bf16* qbf = (bf16*)p; p += BSD * 2;  // reused as ctx after gemm_qkv
  bf16* kbf = (bf16*)p; p += BSD * 2;  // reused as vt  after gemm_qkv
  bf16* vbf = (bf16*)p; p += BSD * 2;
  bf16* qpb = (bf16*)p; p += BSD * 2;
  bf16* kpb = (bf16*)p; p += BSD * 2;
  bf16* vpb = (bf16*)p; p += BSD * 2;
  bf16* wqb = (bf16*)p; p += DD * 2;
  bf16* wkb = (bf16*)p; p += DD * 2;
  bf16* wvb = (bf16*)p; p += DD * 2;
  bf16* wob = (bf16*)p; p += DD * 2;
  bf16* vtb  = kbf;   // safe: kbf dead after gemm_qkv
  bf16* ctxb = qbf;   // safe: qbf dead after gemm_qkv

  cvt_f32_to_bf16<<<2048, 256, 0, stream>>>(q, qbf, (int)(BSD / 4), 1.0f);
  cvt_f32_to_bf16<<<2048, 256, 0, stream>>>(k, kbf, (int)(BSD / 4), 1.0f);
  cvt_f32_to_bf16<<<2048, 256, 0, stream>>>(v, vbf, (int)(BSD / 4), 1.0f);
  cvt_f32_to_bf16<<<1024, 256, 0, stream>>>(Wq, wqb, (int)(DD / 4), 0.125f);  // fold 1/sqrt(HD)
  cvt_f32_to_bf16<<<1024, 256, 0, stream>>>(Wk, wkb, (int)(DD / 4), 1.0f);
  cvt_f32_to_bf16<<<1024, 256, 0, stream>>>(Wv, wvb, (int)(DD / 4), 1.0f);
  cvt_f32_to_bf16<<<1024, 256, 0, stream>>>(Wo, wob, (int)(DD / 4), 1.0f);

  gemm_qkv<<<dim3(Dn / 128, (Bn * Sn) / 128, 3), 256, 0, stream>>>(
      qbf, wqb, qpb, kbf, wkb, kpb, vbf, wvb, vpb);

  transpose_bsd<<<dim3(Sn / 64, Dn / 64, Bn), 256, 0, stream>>>(vpb, vtb);

  flash_attn<<<dim3(Sn / 128, Hn, Bn), 256, 0, stream>>>(qpb, kpb, vtb, ctxb);

  gemm_out_f32<<<dim3(Dn / 128, (Bn * Sn) / 128), 256, 0, stream>>>(ctxb, wob, (float*)d_out);

  (void)in_sizes; (void)n_in; (void)out_size; (void)ws_size;
}

// Round 2
// 205.719 us; speedup vs baseline: 1.0056x; 1.0056x over previous
//
#include <hip/hip_runtime.h>

typedef __bf16 bf16;
typedef __bf16 bf16x4 __attribute__((ext_vector_type(4)));
typedef __bf16 bf16x8 __attribute__((ext_vector_type(8)));
typedef float f32x4 __attribute__((ext_vector_type(4)));

static constexpr int Bn = 2, Sn = 2048, Dn = 1024, Hn = 16, HDn = 64;

__device__ __forceinline__ void gload_lds16(const void* g, void* l) {
  __builtin_amdgcn_global_load_lds((__attribute__((address_space(1))) void*)g,
                                   (__attribute__((address_space(3))) void*)l, 16, 0, 0);
}

__device__ __forceinline__ f32x4 mfma_bf16_16x16x32(bf16x8 a, bf16x8 b, f32x4 c) {
  return __builtin_amdgcn_mfma_f32_16x16x32_bf16(a, b, c, 0, 0, 0);
}

__device__ __forceinline__ float fast_exp2(float x) {
  float r;
  asm("v_exp_f32 %0, %1" : "=v"(r) : "v"(x));
  return r;
}

#define WAITCNT_VM(N) asm volatile("s_waitcnt vmcnt(" #N ")" ::: "memory")
#define WAITCNT_LGKM0 asm volatile("s_waitcnt lgkmcnt(0)" ::: "memory")

// ---------------- fp32 -> bf16 converts (fused launches) ----------------
__global__ __launch_bounds__(256) void cvt_qkv(const float* __restrict__ a0,
                                               const float* __restrict__ a1,
                                               const float* __restrict__ a2,
                                               bf16* __restrict__ o0,
                                               bf16* __restrict__ o1,
                                               bf16* __restrict__ o2, int n4) {
  const float* in = blockIdx.z == 0 ? a0 : (blockIdx.z == 1 ? a1 : a2);
  bf16* out = blockIdx.z == 0 ? o0 : (blockIdx.z == 1 ? o1 : o2);
  int i = blockIdx.x * 256 + threadIdx.x;
  const int stride = gridDim.x * 256;
  for (; i < n4; i += stride) {
    float4 v = reinterpret_cast<const float4*>(in)[i];
    bf16x4 o;
    o[0] = (bf16)v.x; o[1] = (bf16)v.y; o[2] = (bf16)v.z; o[3] = (bf16)v.w;
    reinterpret_cast<bf16x4*>(out)[i] = o;
  }
}

__global__ __launch_bounds__(256) void cvt_w(const float* __restrict__ a0,
                                             const float* __restrict__ a1,
                                             const float* __restrict__ a2,
                                             const float* __restrict__ a3,
                                             bf16* __restrict__ o0,
                                             bf16* __restrict__ o1,
                                             bf16* __restrict__ o2,
                                             bf16* __restrict__ o3,
                                             int n4, float s0) {
  const float* in; bf16* out; float s = 1.0f;
  switch (blockIdx.z) {
    case 0: in = a0; out = o0; s = s0; break;  // Wq gets softmax scale * log2(e)
    case 1: in = a1; out = o1; break;
    case 2: in = a2; out = o2; break;
    default: in = a3; out = o3; break;
  }
  int i = blockIdx.x * 256 + threadIdx.x;
  const int stride = gridDim.x * 256;
  for (; i < n4; i += stride) {
    float4 v = reinterpret_cast<const float4*>(in)[i];
    bf16x4 o;
    o[0] = (bf16)(v.x * s); o[1] = (bf16)(v.y * s);
    o[2] = (bf16)(v.z * s); o[3] = (bf16)(v.w * s);
    reinterpret_cast<bf16x4*>(out)[i] = o;
  }
}

// ---------------- GEMM: C[M,N] = A[M,K] * B[N,K]^T  (m97 structure) ----------------
__device__ __forceinline__ void store_out(float* C, size_t i, float v) { C[i] = v; }
__device__ __forceinline__ void store_out(bf16* C, size_t i, float v) { C[i] = (bf16)v; }

template <typename OutT>
__device__ __forceinline__ void gemm_bt_dev(const bf16* __restrict__ A,
                                            const bf16* __restrict__ Bw,
                                            OutT* __restrict__ C,
                                            int K, int N) {
  const int t = threadIdx.x;
  const int l = t & 63, w = t >> 6;
  const int wr = w >> 1, wc = w & 1;
  const int lc = l & 15, lg = l >> 4;
  const int row0 = blockIdx.y * 128;
  const int col0 = blockIdx.x * 128;

  __shared__ bf16 As[128 * 32];
  __shared__ bf16 Bs[128 * 32];

  f32x4 acc[4][4] = {};

  for (int k0 = 0; k0 < K; k0 += 32) {
#pragma unroll
    for (int i = 0; i < 2; ++i) {
      const int c = i * 256 + t;
      const int r = c >> 2;
      const int scc = (c & 3) ^ (r & 3);
      gload_lds16(A + (size_t)(row0 + r) * K + k0 + scc * 8, As + c * 8);
      gload_lds16(Bw + (size_t)(col0 + r) * K + k0 + scc * 8, Bs + c * 8);
    }
    __syncthreads();

    bf16x8 af[4], bfr[4];
#pragma unroll
    for (int m = 0; m < 4; ++m) {
      const int r = wr * 64 + m * 16 + lc;
      af[m] = *reinterpret_cast<const bf16x8*>(As + r * 32 + ((lg ^ (r & 3)) * 8));
    }
#pragma unroll
    for (int n = 0; n < 4; ++n) {
      const int r = wc * 64 + n * 16 + lc;
      bfr[n] = *reinterpret_cast<const bf16x8*>(Bs + r * 32 + ((lg ^ (r & 3)) * 8));
    }
#pragma unroll
    for (int m = 0; m < 4; ++m)
#pragma unroll
      for (int n = 0; n < 4; ++n)
        acc[m][n] = mfma_bf16_16x16x32(af[m], bfr[n], acc[m][n]);
    __syncthreads();
  }

#pragma unroll
  for (int m = 0; m < 4; ++m) {
    const int rbase = row0 + wr * 64 + m * 16 + lg * 4;
#pragma unroll
    for (int n = 0; n < 4; ++n) {
      const int col = col0 + wc * 64 + n * 16 + lc;
#pragma unroll
      for (int j = 0; j < 4; ++j)
        store_out(C, (size_t)(rbase + j) * N + col, acc[m][n][j]);
    }
  }
}

__global__ __launch_bounds__(256) void gemm_qkv(
    const bf16* __restrict__ qa, const bf16* __restrict__ wq, bf16* __restrict__ qo,
    const bf16* __restrict__ ka, const bf16* __restrict__ wk, bf16* __restrict__ ko,
    const bf16* __restrict__ va, const bf16* __restrict__ wv, bf16* __restrict__ vo) {
  const bf16 *A, *Bw;
  bf16* C;
  if (blockIdx.z == 0)      { A = qa; Bw = wq; C = qo; }
  else if (blockIdx.z == 1) { A = ka; Bw = wk; C = ko; }
  else                      { A = va; Bw = wv; C = vo; }
  gemm_bt_dev<bf16>(A, Bw, C, Dn, Dn);
}

__global__ __launch_bounds__(256) void gemm_out_f32(const bf16* __restrict__ A,
                                                    const bf16* __restrict__ Bw,
                                                    float* __restrict__ C) {
  gemm_bt_dev<float>(A, Bw, C, Dn, Dn);
}

// ---------------- per-batch transpose (S x D) -> (D x S) for V ----------------
__global__ __launch_bounds__(256) void transpose_bsd(const bf16* __restrict__ in,
                                                     bf16* __restrict__ out) {
  __shared__ bf16 tile[64][66];
  const int s0 = blockIdx.x * 64, d0 = blockIdx.y * 64, b = blockIdx.z;
  const int t = threadIdx.x;
#pragma unroll
  for (int i = 0; i < 2; ++i) {
    const int c = i * 256 + t;
    const int r = c >> 3, cc = (c & 7) * 8;
    const bf16x8 v = *reinterpret_cast<const bf16x8*>(
        in + ((size_t)b * Sn + s0 + r) * Dn + d0 + cc);
#pragma unroll
    for (int j = 0; j < 8; ++j) tile[r][cc + j] = v[j];
  }
  __syncthreads();
#pragma unroll
  for (int i = 0; i < 2; ++i) {
    const int c = i * 256 + t;
    const int r = c >> 3, cc = (c & 7) * 8;
    bf16x8 v;
#pragma unroll
    for (int j = 0; j < 8; ++j) v[j] = tile[cc + j][r];
    *reinterpret_cast<bf16x8*>(out + ((size_t)b * Dn + d0 + r) * Sn + s0 + cc) = v;
  }
}

// ---------------- causal flash attention (v2: dbuf pipeline, 64-row blocks) ----------------
// qp pre-scaled by (1/8)*log2(e) via Wq; softmax in exp2 domain (mathematically identical).
// qp,kp: (B,S,D); vt: (B,D,S); ctx: (B,S,D)
__global__ __launch_bounds__(256) void flash_attn(const bf16* __restrict__ qp,
                                                  const bf16* __restrict__ kp,
                                                  const bf16* __restrict__ vt,
                                                  bf16* __restrict__ ctx) {
  const int qt = blockIdx.x;   // 32 Q-tiles of 64 rows
  const int h  = blockIdx.y;   // 16
  const int b  = blockIdx.z;   // 2
  const int q0 = qt * 64;
  const int t = threadIdx.x, w = t >> 6, l = t & 63;
  const int lc = l & 15, lg = l >> 4;
  const int qrow0 = q0 + w * 16;  // each wave owns 16 Q rows

  __shared__ bf16 Klds[2][64 * 64];   // [buf][kv][d], chunk-XOR swizzled
  __shared__ bf16 Vlds[2][64 * 64];   // [buf][d][kv], chunk-XOR swizzled
  __shared__ bf16 Plds[4][16 * 64];   // per-wave P, chunk-XOR swizzled (stride 64)
  // total LDS = 40960 B -> up to 4 blocks/CU

  // staging addresses (2 chunks each for K and V per thread)
  const bf16* ksrc[2];
  const bf16* vsrc[2];
  int cofs[2];
#pragma unroll
  for (int i = 0; i < 2; ++i) {
    const int c = i * 256 + t;
    const int r = c >> 3;
    const int scc = (c & 7) ^ (r & 7);
    ksrc[i] = kp + ((size_t)b * Sn + r) * Dn + h * HDn + scc * 8;
    vsrc[i] = vt + ((size_t)b * Dn + h * HDn + r) * Sn + scc * 8;
    cofs[i] = c * 8;
  }

  auto STAGE = [&](int buf, int kv0) {
#pragma unroll
    for (int i = 0; i < 2; ++i) {
      gload_lds16(ksrc[i] + (size_t)kv0 * Dn, &Klds[buf][cofs[i]]);
      gload_lds16(vsrc[i] + kv0,              &Vlds[buf][cofs[i]]);
    }
  };

  // Q fragments in registers (A-operand layout, 16 rows x 64 cols)
  bf16x8 qf[2];
#pragma unroll
  for (int kk = 0; kk < 2; ++kk)
    qf[kk] = *reinterpret_cast<const bf16x8*>(
        qp + ((size_t)b * Sn + qrow0 + lc) * Dn + h * HDn + kk * 32 + lg * 8);

  float mrow[4], lrow[4];
  f32x4 oacc[4] = {};
#pragma unroll
  for (int j = 0; j < 4; ++j) { mrow[j] = -1e30f; lrow[j] = 0.0f; }

  const int nkv = qt + 1;
  int cur = 0;
  STAGE(0, 0);

  for (int kt = 0; kt < nkv; ++kt) {
    if (kt + 1 < nkv) {
      STAGE(cur ^ 1, (kt + 1) * 64);  // prefetch next tile
      WAITCNT_VM(4);                  // current tile done; 4 prefetch loads in flight
    } else {
      WAITCNT_VM(0);
    }
    __builtin_amdgcn_s_barrier();
    __builtin_amdgcn_sched_barrier(0);

    const char* Kc = (const char*)&Klds[cur][0];
    const char* Vc = (const char*)&Vlds[cur][0];

    // S = Q K^T (16 x 64)
    f32x4 sc[4] = {};
    __builtin_amdgcn_s_setprio(1);
#pragma unroll
    for (int kk = 0; kk < 2; ++kk) {
#pragma unroll
      for (int n = 0; n < 4; ++n) {
        const int r = n * 16 + lc;
        const int off = (r << 7) + (((kk * 4 + lg) ^ (r & 7)) << 4);
        const bf16x8 kf = *reinterpret_cast<const bf16x8*>(Kc + off);
        sc[n] = mfma_bf16_16x16x32(qf[kk], kf, sc[n]);
      }
    }
    __builtin_amdgcn_s_setprio(0);

    // causal mask: only the last tile crosses the diagonal (tiles aligned 64/64)
    if (kt == nkv - 1) {
      const int kv0 = kt * 64;
      const int rg = qrow0 + lg * 4;
#pragma unroll
      for (int n = 0; n < 4; ++n) {
        const int cg = kv0 + n * 16 + lc;
#pragma unroll
        for (int j = 0; j < 4; ++j)
          if (cg > rg + j) sc[n][j] = -1e30f;
      }
    }

    // online softmax (exp2 domain), wave-parallel over 16-lane row groups
    float tmax[4], rsum[4], alpha[4];
#pragma unroll
    for (int j = 0; j < 4; ++j)
      tmax[j] = fmaxf(fmaxf(sc[0][j], sc[1][j]), fmaxf(sc[2][j], sc[3][j]));
#pragma unroll
    for (int dd = 1; dd < 16; dd <<= 1)
#pragma unroll
      for (int j = 0; j < 4; ++j)
        tmax[j] = fmaxf(tmax[j], __shfl_xor(tmax[j], dd, 64));
#pragma unroll
    for (int j = 0; j < 4; ++j) {
      const float mn = fmaxf(mrow[j], tmax[j]);
      alpha[j] = fast_exp2(mrow[j] - mn);
      mrow[j] = mn;
      rsum[j] = 0.0f;
    }
#pragma unroll
    for (int n = 0; n < 4; ++n)
#pragma unroll
      for (int j = 0; j < 4; ++j) {
        const float pe = fast_exp2(sc[n][j] - mrow[j]);
        sc[n][j] = pe;
        rsum[j] += pe;
      }
#pragma unroll
    for (int dd = 1; dd < 16; dd <<= 1)
#pragma unroll
      for (int j = 0; j < 4; ++j)
        rsum[j] += __shfl_xor(rsum[j], dd, 64);
#pragma unroll
    for (int j = 0; j < 4; ++j)
      lrow[j] = lrow[j] * alpha[j] + rsum[j];
#pragma unroll
    for (int n = 0; n < 4; ++n)
#pragma unroll
      for (int j = 0; j < 4; ++j)
        oacc[n][j] *= alpha[j];

    // P -> LDS (bf16), per-wave slab, chunk-XOR swizzle on 16B chunks
#pragma unroll
    for (int n = 0; n < 4; ++n)
#pragma unroll
      for (int j = 0; j < 4; ++j) {
        const int row = lg * 4 + j;
        const int col = n * 16 + lc;
        Plds[w][row * 64 + (((col >> 3) ^ (row & 7)) << 3) + (col & 7)] =
            (bf16)sc[n][j];
      }
    WAITCNT_LGKM0;  // cross-lane P visibility within the wave
    __builtin_amdgcn_sched_barrier(0);

    // O += P V
    __builtin_amdgcn_s_setprio(1);
#pragma unroll
    for (int kk = 0; kk < 2; ++kk) {
      const bf16x8 pa = *reinterpret_cast<const bf16x8*>(
          &Plds[w][lc * 64 + (((kk * 4 + lg) ^ (lc & 7)) << 3)]);
#pragma unroll
      for (int nd = 0; nd < 4; ++nd) {
        const int r = nd * 16 + lc;
        const int off = (r << 7) + (((kk * 4 + lg) ^ (r & 7)) << 4);
        const bf16x8 vb = *reinterpret_cast<const bf16x8*>(Vc + off);
        oacc[nd] = mfma_bf16_16x16x32(pa, vb, oacc[nd]);
      }
    }
    __builtin_amdgcn_s_setprio(0);

    WAITCNT_LGKM0;  // all LDS reads of buf[cur] retired before it is restaged
    __builtin_amdgcn_s_barrier();
    __builtin_amdgcn_sched_barrier(0);
    cur ^= 1;
  }

  // epilogue: O / l -> ctx (bf16)
#pragma unroll
  for (int j = 0; j < 4; ++j) {
    const float inv = 1.0f / lrow[j];
    const int rg = qrow0 + lg * 4 + j;
#pragma unroll
    for (int nd = 0; nd < 4; ++nd)
      ctx[((size_t)b * Sn + rg) * Dn + h * HDn + nd * 16 + lc] =
          (bf16)(oacc[nd][j] * inv);
  }
}

// ---------------- launch ----------------
extern "C" void kernel_launch(void* const* d_in, const int* in_sizes, int n_in,
                              void* d_out, int out_size, void* d_ws, size_t ws_size,
                              hipStream_t stream) {
  const float* q  = (const float*)d_in[0];
  const float* k  = (const float*)d_in[1];
  const float* v  = (const float*)d_in[2];
  // d_in[3] = causal mask (structure known; unused)
  const float* Wq = (const float*)d_in[4];
  const float* Wk = (const float*)d_in[5];
  const float* Wv = (const float*)d_in[6];
  const float* Wo = (const float*)d_in[7];

  constexpr size_t BSD = (size_t)Bn * Sn * Dn;
  constexpr size_t DD  = (size_t)Dn * Dn;

  char* p = (char*)d_ws;
  bf16* qbf = (bf16*)p; p += BSD * 2;
  bf16* kbf = (bf16*)p; p += BSD * 2;
  bf16* vbf = (bf16*)p; p += BSD * 2;
  bf16* qpb = (bf16*)p; p += BSD * 2;
  bf16* kpb = (bf16*)p; p += BSD * 2;
  bf16* vpb = (bf16*)p; p += BSD * 2;
  bf16* wqb = (bf16*)p; p += DD * 2;
  bf16* wkb = (bf16*)p; p += DD * 2;
  bf16* wvb = (bf16*)p; p += DD * 2;
  bf16* wob = (bf16*)p; p += DD * 2;
  bf16* vtb  = kbf;   // kbf dead after gemm_qkv
  bf16* ctxb = qbf;   // qbf dead after gemm_qkv

  // fold softmax scale (1/sqrt(64)=1/8) and log2(e) into Wq for exp2-domain softmax
  const float wq_scale = 0.125f * 1.4426950408889634f;

  cvt_qkv<<<dim3(1024, 1, 3), 256, 0, stream>>>(q, k, v, qbf, kbf, vbf, (int)(BSD / 4));
  cvt_w<<<dim3(256, 1, 4), 256, 0, stream>>>(Wq, Wk, Wv, Wo, wqb, wkb, wvb, wob,
                                             (int)(DD / 4), wq_scale);

  gemm_qkv<<<dim3(Dn / 128, (Bn * Sn) / 128, 3), 256, 0, stream>>>(
      qbf, wqb, qpb, kbf, wkb, kpb, vbf, wvb, vpb);

  transpose_bsd<<<dim3(Sn / 64, Dn / 64, Bn), 256, 0, stream>>>(vpb, vtb);

  flash_attn<<<dim3(Sn / 64, Hn, Bn), 256, 0, stream>>>(qpb, kpb, vtb, ctxb);

  gemm_out_f32<<<dim3(Dn / 128, (Bn * Sn) / 128), 256, 0, stream>>>(ctxb, wob, (float*)d_out);

  (void)in_sizes; (void)n_in; (void)out_size; (void)ws_size;
}

// Round 5
// 156.651 us; speedup vs baseline: 1.3206x; 1.3132x over previous
//
#include <hip/hip_runtime.h>

typedef __bf16 bf16;
typedef __bf16 bf16x4 __attribute__((ext_vector_type(4)));
typedef __bf16 bf16x8 __attribute__((ext_vector_type(8)));
typedef float f32x4 __attribute__((ext_vector_type(4)));
typedef float f32x16 __attribute__((ext_vector_type(16)));
typedef unsigned u32x4 __attribute__((ext_vector_type(4)));

static constexpr int Bn = 2, Sn = 2048, Dn = 1024, Hn = 16, HDn = 64;

__device__ __forceinline__ void gload_lds16(const void* g, void* l) {
  __builtin_amdgcn_global_load_lds((__attribute__((address_space(1))) void*)g,
                                   (__attribute__((address_space(3))) void*)l, 16, 0, 0);
}

__device__ __forceinline__ f32x4 mfma_bf16_16x16x32(bf16x8 a, bf16x8 b, f32x4 c) {
  return __builtin_amdgcn_mfma_f32_16x16x32_bf16(a, b, c, 0, 0, 0);
}

__device__ __forceinline__ f32x16 mfma_bf16_32x32x16(bf16x8 a, bf16x8 b, f32x16 c) {
  return __builtin_amdgcn_mfma_f32_32x32x16_bf16(a, b, c, 0, 0, 0);
}

__device__ __forceinline__ float fast_exp2(float x) {
  float r;
  asm("v_exp_f32 %0, %1" : "=v"(r) : "v"(x));
  return r;
}

__device__ __forceinline__ unsigned cvt_pk_bf16(float lo, float hi) {
  unsigned r;
  asm("v_cvt_pk_bf16_f32 %0, %1, %2" : "=v"(r) : "v"(lo), "v"(hi));
  return r;
}

// Cross-half (lane ^ 32) combine via known-good shfl_xor (ds_bpermute path).
// R3/R4 used hand-written v_permlane32_swap asm here; two NaN rounds isolated
// that instruction as the only unverified link. shfl is slower (~2us total)
// but has unambiguous semantics.
__device__ __forceinline__ float cross_half_max(float v) {
  return fmaxf(v, __shfl_xor(v, 32, 64));
}
__device__ __forceinline__ float cross_half_add(float v) {
  return v + __shfl_xor(v, 32, 64);
}
__device__ __forceinline__ unsigned shfl32u(unsigned u) {
  return (unsigned)__shfl_xor((int)u, 32, 64);
}

#define WAITCNT_VM(N) asm volatile("s_waitcnt vmcnt(" #N ")" ::: "memory")
#define WAITCNT_LGKM0 asm volatile("s_waitcnt lgkmcnt(0)" ::: "memory")

// ---------------- fp32 -> bf16 converts (fused launches) ----------------
__global__ __launch_bounds__(256) void cvt_qkv(const float* __restrict__ a0,
                                               const float* __restrict__ a1,
                                               const float* __restrict__ a2,
                                               bf16* __restrict__ o0,
                                               bf16* __restrict__ o1,
                                               bf16* __restrict__ o2, int n4) {
  const float* in = blockIdx.z == 0 ? a0 : (blockIdx.z == 1 ? a1 : a2);
  bf16* out = blockIdx.z == 0 ? o0 : (blockIdx.z == 1 ? o1 : o2);
  int i = blockIdx.x * 256 + threadIdx.x;
  const int stride = gridDim.x * 256;
  for (; i < n4; i += stride) {
    float4 v = reinterpret_cast<const float4*>(in)[i];
    bf16x4 o;
    o[0] = (bf16)v.x; o[1] = (bf16)v.y; o[2] = (bf16)v.z; o[3] = (bf16)v.w;
    reinterpret_cast<bf16x4*>(out)[i] = o;
  }
}

__global__ __launch_bounds__(256) void cvt_w(const float* __restrict__ a0,
                                             const float* __restrict__ a1,
                                             const float* __restrict__ a2,
                                             const float* __restrict__ a3,
                                             bf16* __restrict__ o0,
                                             bf16* __restrict__ o1,
                                             bf16* __restrict__ o2,
                                             bf16* __restrict__ o3,
                                             int n4, float s0) {
  const float* in; bf16* out; float s = 1.0f;
  switch (blockIdx.z) {
    case 0: in = a0; out = o0; s = s0; break;  // Wq gets softmax scale * log2(e)
    case 1: in = a1; out = o1; break;
    case 2: in = a2; out = o2; break;
    default: in = a3; out = o3; break;
  }
  int i = blockIdx.x * 256 + threadIdx.x;
  const int stride = gridDim.x * 256;
  for (; i < n4; i += stride) {
    float4 v = reinterpret_cast<const float4*>(in)[i];
    bf16x4 o;
    o[0] = (bf16)(v.x * s); o[1] = (bf16)(v.y * s);
    o[2] = (bf16)(v.z * s); o[3] = (bf16)(v.w * s);
    reinterpret_cast<bf16x4*>(out)[i] = o;
  }
}

// ---------------- GEMM: C[M,N] = A[M,K] * B[N,K]^T  (m97 structure) ----------------
__device__ __forceinline__ void store_out(float* C, size_t i, float v) { C[i] = v; }
__device__ __forceinline__ void store_out(bf16* C, size_t i, float v) { C[i] = (bf16)v; }

template <typename OutT>
__device__ __forceinline__ void gemm_bt_dev(const bf16* __restrict__ A,
                                            const bf16* __restrict__ Bw,
                                            OutT* __restrict__ C,
                                            int K, int N) {
  const int t = threadIdx.x;
  const int l = t & 63, w = t >> 6;
  const int wr = w >> 1, wc = w & 1;
  const int lc = l & 15, lg = l >> 4;
  const int row0 = blockIdx.y * 128;
  const int col0 = blockIdx.x * 128;

  __shared__ bf16 As[128 * 32];
  __shared__ bf16 Bs[128 * 32];

  f32x4 acc[4][4] = {};

  for (int k0 = 0; k0 < K; k0 += 32) {
#pragma unroll
    for (int i = 0; i < 2; ++i) {
      const int c = i * 256 + t;
      const int r = c >> 2;
      const int scc = (c & 3) ^ (r & 3);
      gload_lds16(A + (size_t)(row0 + r) * K + k0 + scc * 8, As + c * 8);
      gload_lds16(Bw + (size_t)(col0 + r) * K + k0 + scc * 8, Bs + c * 8);
    }
    __syncthreads();

    bf16x8 af[4], bfr[4];
#pragma unroll
    for (int m = 0; m < 4; ++m) {
      const int r = wr * 64 + m * 16 + lc;
      af[m] = *reinterpret_cast<const bf16x8*>(As + r * 32 + ((lg ^ (r & 3)) * 8));
    }
#pragma unroll
    for (int n = 0; n < 4; ++n) {
      const int r = wc * 64 + n * 16 + lc;
      bfr[n] = *reinterpret_cast<const bf16x8*>(Bs + r * 32 + ((lg ^ (r & 3)) * 8));
    }
#pragma unroll
    for (int m = 0; m < 4; ++m)
#pragma unroll
      for (int n = 0; n < 4; ++n)
        acc[m][n] = mfma_bf16_16x16x32(af[m], bfr[n], acc[m][n]);
    __syncthreads();
  }

#pragma unroll
  for (int m = 0; m < 4; ++m) {
    const int rbase = row0 + wr * 64 + m * 16 + lg * 4;
#pragma unroll
    for (int n = 0; n < 4; ++n) {
      const int col = col0 + wc * 64 + n * 16 + lc;
#pragma unroll
      for (int j = 0; j < 4; ++j)
        store_out(C, (size_t)(rbase + j) * N + col, acc[m][n][j]);
    }
  }
}

__global__ __launch_bounds__(256) void gemm_qkv(
    const bf16* __restrict__ qa, const bf16* __restrict__ wq, bf16* __restrict__ qo,
    const bf16* __restrict__ ka, const bf16* __restrict__ wk, bf16* __restrict__ ko,
    const bf16* __restrict__ va, const bf16* __restrict__ wv, bf16* __restrict__ vo) {
  const bf16 *A, *Bw;
  bf16* C;
  if (blockIdx.z == 0)      { A = qa; Bw = wq; C = qo; }
  else if (blockIdx.z == 1) { A = ka; Bw = wk; C = ko; }
  else                      { A = va; Bw = wv; C = vo; }
  gemm_bt_dev<bf16>(A, Bw, C, Dn, Dn);
}

__global__ __launch_bounds__(256) void gemm_out_f32(const bf16* __restrict__ A,
                                                    const bf16* __restrict__ Bw,
                                                    float* __restrict__ C) {
  gemm_bt_dev<float>(A, Bw, C, Dn, Dn);
}

// ---------------- per-batch transpose (S x D) -> (D x S) for V ----------------
__global__ __launch_bounds__(256) void transpose_bsd(const bf16* __restrict__ in,
                                                     bf16* __restrict__ out) {
  __shared__ bf16 tile[64][66];
  const int s0 = blockIdx.x * 64, d0 = blockIdx.y * 64, b = blockIdx.z;
  const int t = threadIdx.x;
#pragma unroll
  for (int i = 0; i < 2; ++i) {
    const int c = i * 256 + t;
    const int r = c >> 3, cc = (c & 7) * 8;
    const bf16x8 v = *reinterpret_cast<const bf16x8*>(
        in + ((size_t)b * Sn + s0 + r) * Dn + d0 + cc);
#pragma unroll
    for (int j = 0; j < 8; ++j) tile[r][cc + j] = v[j];
  }
  __syncthreads();
#pragma unroll
  for (int i = 0; i < 2; ++i) {
    const int c = i * 256 + t;
    const int r = c >> 3, cc = (c & 7) * 8;
    bf16x8 v;
#pragma unroll
    for (int j = 0; j < 8; ++j) v[j] = tile[cc + j][r];
    *reinterpret_cast<bf16x8*>(out + ((size_t)b * Dn + d0 + r) * Sn + s0 + cc) = v;
  }
}

// ---------------- causal flash attention (v3c: swapped 32x32 MFMA, shfl exchanges) -------
// qp pre-scaled by (1/8)*log2(e) via Wq; softmax in exp2 domain.
// qp,kp: (B,S,D); vt: (B,D,S); ctx: (B,S,D)
// 4 waves/block, wave owns 32 Q rows (QBLK=128), KVBLK=64.
// S^T = mfma(K, Q): q = lane&31, kv(reg,hi) = (r&3)+8*(r>>2)+4*hi  -> softmax per-lane.
// O^T = mfma(V^T, P): q = lane&31, d per-reg -> alpha/1/l are per-lane scalars.
__global__ __launch_bounds__(256) void flash_attn(const bf16* __restrict__ qp,
                                                  const bf16* __restrict__ kp,
                                                  const bf16* __restrict__ vt,
                                                  bf16* __restrict__ ctx) {
  const int qt = 15 - blockIdx.x;  // reversed: heavy blocks dispatch first
  const int h  = blockIdx.y;
  const int b  = blockIdx.z;
  const int t = threadIdx.x, w = t >> 6, l = t & 63;
  const int lq = l & 31, hi = l >> 5;
  const int qrow0 = qt * 128 + w * 32;  // wave's 32 Q rows

  __shared__ char smem[32768];  // K: 2 x 8KB | V: 2 x 8KB ; reused as epilogue scratch

  // staging addresses (2 chunks each for K and V per thread), chunk-XOR pre-swizzled source
  const bf16* ksrc[2];
  const bf16* vsrc[2];
  int cofs[2];
#pragma unroll
  for (int i = 0; i < 2; ++i) {
    const int c = i * 256 + t;
    const int r = c >> 3;
    const int scc = (c & 7) ^ (r & 7);
    ksrc[i] = kp + ((size_t)b * Sn + r) * Dn + h * HDn + scc * 8;
    vsrc[i] = vt + ((size_t)b * Dn + h * HDn + r) * Sn + scc * 8;
    cofs[i] = c * 8;
  }

  auto STAGE = [&](int buf, int kv0) {
    bf16* Kd = (bf16*)(smem + buf * 8192);
    bf16* Vd = (bf16*)(smem + 16384 + buf * 8192);
#pragma unroll
    for (int i = 0; i < 2; ++i) {
      gload_lds16(ksrc[i] + (size_t)kv0 * Dn, Kd + cofs[i]);
      gload_lds16(vsrc[i] + kv0,              Vd + cofs[i]);
    }
  };

  // Q fragments (B-operand of swapped QK^T): lane holds q=lq, k = kk*16 + hi*8 + e
  bf16x8 qf[4];
#pragma unroll
  for (int kk = 0; kk < 4; ++kk)
    qf[kk] = *reinterpret_cast<const bf16x8*>(
        qp + ((size_t)b * Sn + qrow0 + lq) * Dn + h * HDn + kk * 16 + hi * 8);

  f32x16 oacc0 = {}, oacc1 = {};  // O^T: d 0..31 / 32..63 (per-reg), q = lq
  float mrow = -1e30f, lsum = 0.0f;

  const int nkv = 2 * qt + 2;
  int cur = 0;
  STAGE(0, 0);

  for (int kt = 0; kt < nkv; ++kt) {
    if (kt + 1 < nkv) {
      STAGE(cur ^ 1, (kt + 1) * 64);
      WAITCNT_VM(4);
    } else {
      WAITCNT_VM(0);
    }
    __builtin_amdgcn_s_barrier();
    __builtin_amdgcn_sched_barrier(0);

    const int kv0 = kt * 64;
    if (kv0 <= qrow0 + 31) {  // wave-uniform causal skip
      const char* Kc = smem + cur * 8192;
      const char* Vc = smem + 16384 + cur * 8192;

      // S^T = K Q^T : two 32-kv tiles
      f32x16 s0 = {}, s1 = {};
      __builtin_amdgcn_s_setprio(1);
#pragma unroll
      for (int kk = 0; kk < 4; ++kk) {
        const int ch = kk * 2 + hi;
        const int r0 = lq, r1 = 32 + lq;
        const bf16x8 k0 = *reinterpret_cast<const bf16x8*>(Kc + r0 * 128 + ((ch ^ (r0 & 7)) << 4));
        const bf16x8 k1 = *reinterpret_cast<const bf16x8*>(Kc + r1 * 128 + ((ch ^ (r1 & 7)) << 4));
        s0 = mfma_bf16_32x32x16(k0, qf[kk], s0);
        s1 = mfma_bf16_32x32x16(k1, qf[kk], s1);
      }
      __builtin_amdgcn_s_setprio(0);

      // causal mask (diagonal tiles only)
      if (kv0 + 63 > qrow0) {
        const int qg = qrow0 + lq;
#pragma unroll
        for (int r = 0; r < 16; ++r) {
          const int kvl = (r & 3) + 8 * (r >> 2) + 4 * hi;
          if (kv0 + kvl > qg)      s0[r] = -1e30f;
          if (kv0 + 32 + kvl > qg) s1[r] = -1e30f;
        }
      }

      // in-register online softmax (per-lane row q = lq)
      float mx[8];
#pragma unroll
      for (int i = 0; i < 8; ++i)
        mx[i] = fmaxf(fmaxf(s0[i], s0[i + 8]), fmaxf(s1[i], s1[i + 8]));
#pragma unroll
      for (int i = 0; i < 4; ++i) mx[i] = fmaxf(mx[i], mx[i + 4]);
      const float tmax_own = fmaxf(fmaxf(mx[0], mx[1]), fmaxf(mx[2], mx[3]));
      const float tmax = cross_half_max(tmax_own);
      const float mn = fmaxf(mrow, fmaxf(tmax_own, tmax));  // no-overflow invariant
      const float alpha = fast_exp2(mrow - mn);
      mrow = mn;
#pragma unroll
      for (int r = 0; r < 16; ++r) {
        s0[r] = fast_exp2(s0[r] - mn);
        s1[r] = fast_exp2(s1[r] - mn);
      }
      float sm[8];
#pragma unroll
      for (int i = 0; i < 8; ++i)
        sm[i] = (s0[i] + s0[i + 8]) + (s1[i] + s1[i + 8]);
#pragma unroll
      for (int i = 0; i < 4; ++i) sm[i] += sm[i + 4];
      float rsum = (sm[0] + sm[1]) + (sm[2] + sm[3]);
      rsum = cross_half_add(rsum);
      lsum = lsum * alpha + rsum;
#pragma unroll
      for (int r = 0; r < 16; ++r) { oacc0[r] *= alpha; oacc1[r] *= alpha; }

      // P -> bf16 B-fragments, cross-half redistribution via shfl_xor + select.
      // Lane (lq,hi) owns kv {4hi+0..3, 4hi+8..11, ...} packed as words
      // u0=(base+0,1) u1=(base+2,3) u2=(base+8,9) u3=(base+10,11) with base=4hi.
      // B-frag needs kv 8hi+0..7 as 4 words:
      //   hi=0: [own u0, own u1, partner u0, partner u1]
      //   hi=1: [partner u2, partner u3, own u2, own u3]
      u32x4 pw[4];
#pragma unroll
      for (int c2 = 0; c2 < 4; ++c2) {
        const f32x16& S = (c2 < 2) ? s0 : s1;
        const int base = (c2 & 1) * 8;
        const unsigned u0 = cvt_pk_bf16(S[base + 0], S[base + 1]);
        const unsigned u1 = cvt_pk_bf16(S[base + 2], S[base + 3]);
        const unsigned u2 = cvt_pk_bf16(S[base + 4], S[base + 5]);
        const unsigned u3 = cvt_pk_bf16(S[base + 6], S[base + 7]);
        const unsigned p0 = shfl32u(u0);
        const unsigned p1 = shfl32u(u1);
        const unsigned p2 = shfl32u(u2);
        const unsigned p3 = shfl32u(u3);
        pw[c2][0] = hi ? p2 : u0;
        pw[c2][1] = hi ? p3 : u1;
        pw[c2][2] = hi ? u2 : p0;
        pw[c2][3] = hi ? u3 : p1;
      }

      // O^T += V^T P : A = V^T (d rows), B = P (q cols)
      __builtin_amdgcn_s_setprio(1);
#pragma unroll
      for (int kk = 0; kk < 4; ++kk) {
        const bf16x8 pf = __builtin_bit_cast(bf16x8, pw[kk]);
        const int ch = kk * 2 + hi;
        const int r0 = lq, r1 = 32 + lq;
        const bf16x8 v0 = *reinterpret_cast<const bf16x8*>(Vc + r0 * 128 + ((ch ^ (r0 & 7)) << 4));
        const bf16x8 v1 = *reinterpret_cast<const bf16x8*>(Vc + r1 * 128 + ((ch ^ (r1 & 7)) << 4));
        oacc0 = mfma_bf16_32x32x16(v0, pf, oacc0);
        oacc1 = mfma_bf16_32x32x16(v1, pf, oacc1);
      }
      __builtin_amdgcn_s_setprio(0);
    }

    WAITCNT_LGKM0;
    __builtin_amdgcn_s_barrier();
    __builtin_amdgcn_sched_barrier(0);
    cur ^= 1;
  }

  // epilogue: O^T/l -> per-wave LDS transpose -> coalesced global stores
  const float inv = 1.0f / lsum;
  bf16* ep = (bf16*)(smem + w * 8192);  // [32 q][72 d] bf16 (144B rows, 16B-aligned)
#pragma unroll
  for (int dt = 0; dt < 2; ++dt) {
    const f32x16& O = dt ? oacc1 : oacc0;
#pragma unroll
    for (int g = 0; g < 4; ++g) {
      bf16x4 o4;
#pragma unroll
      for (int j = 0; j < 4; ++j) o4[j] = (bf16)(O[g * 4 + j] * inv);
      const int d = dt * 32 + g * 8 + hi * 4;
      *reinterpret_cast<bf16x4*>(&ep[lq * 72 + d]) = o4;
    }
  }
  WAITCNT_LGKM0;
  __builtin_amdgcn_sched_barrier(0);
#pragma unroll
  for (int i = 0; i < 4; ++i) {
    const int q = i * 8 + (l >> 3);
    const int d0 = (l & 7) * 8;
    const bf16x8 vv = *reinterpret_cast<const bf16x8*>(&ep[q * 72 + d0]);
    *reinterpret_cast<bf16x8*>(
        &ctx[((size_t)b * Sn + qt * 128 + w * 32 + q) * Dn + h * HDn + d0]) = vv;
  }
}

// ---------------- launch ----------------
extern "C" void kernel_launch(void* const* d_in, const int* in_sizes, int n_in,
                              void* d_out, int out_size, void* d_ws, size_t ws_size,
                              hipStream_t stream) {
  const float* q  = (const float*)d_in[0];
  const float* k  = (const float*)d_in[1];
  const float* v  = (const float*)d_in[2];
  // d_in[3] = causal mask (structure known; unused)
  const float* Wq = (const float*)d_in[4];
  const float* Wk = (const float*)d_in[5];
  const float* Wv = (const float*)d_in[6];
  const float* Wo = (const float*)d_in[7];

  constexpr size_t BSD = (size_t)Bn * Sn * Dn;
  constexpr size_t DD  = (size_t)Dn * Dn;

  char* p = (char*)d_ws;
  bf16* qbf = (bf16*)p; p += BSD * 2;
  bf16* kbf = (bf16*)p; p += BSD * 2;
  bf16* vbf = (bf16*)p; p += BSD * 2;
  bf16* qpb = (bf16*)p; p += BSD * 2;
  bf16* kpb = (bf16*)p; p += BSD * 2;
  bf16* vpb = (bf16*)p; p += BSD * 2;
  bf16* wqb = (bf16*)p; p += DD * 2;
  bf16* wkb = (bf16*)p; p += DD * 2;
  bf16* wvb = (bf16*)p; p += DD * 2;
  bf16* wob = (bf16*)p; p += DD * 2;
  bf16* vtb  = kbf;   // kbf dead after gemm_qkv
  bf16* ctxb = qbf;   // qbf dead after gemm_qkv

  // fold softmax scale (1/sqrt(64)=1/8) and log2(e) into Wq for exp2-domain softmax
  const float wq_scale = 0.125f * 1.4426950408889634f;

  cvt_qkv<<<dim3(1024, 1, 3), 256, 0, stream>>>(q, k, v, qbf, kbf, vbf, (int)(BSD / 4));
  cvt_w<<<dim3(256, 1, 4), 256, 0, stream>>>(Wq, Wk, Wv, Wo, wqb, wkb, wvb, wob,
                                             (int)(DD / 4), wq_scale);

  gemm_qkv<<<dim3(Dn / 128, (Bn * Sn) / 128, 3), 256, 0, stream>>>(
      qbf, wqb, qpb, kbf, wkb, kpb, vbf, wvb, vpb);

  transpose_bsd<<<dim3(Sn / 64, Dn / 64, Bn), 256, 0, stream>>>(vpb, vtb);

  flash_attn<<<dim3(16, Hn, Bn), 256, 0, stream>>>(qpb, kpb, vtb, ctxb);

  gemm_out_f32<<<dim3(Dn / 128, (Bn * Sn) / 128), 256, 0, stream>>>(ctxb, wob, (float*)d_out);

  (void)in_sizes; (void)n_in; (void)out_size; (void)ws_size;
}